// Round 14
// baseline (1976.800 us; speedup 1.0000x reference)
//
#include <hip/hip_runtime.h>

// ---------------------------------------------------------------------------
// Encoder: x=emb[enc]; xp = x@Wx + b_in; reset-after GRU over T=256 steps;
// out = h_last[:, 200:700].  All float inputs fp32; output fp32.
//
// Persistent weight-stationary GRU, per-WAVE dataflow sync:
//   - Consumer wave rt reads ONLY its own 16 rows, produced by same-rt waves
//     of the 22 producer blocks. Producer drains own stores (vmcnt(0) is
//     wave-local) then publishes flag[g][slice][wave]; consumer polls its 44
//     flags lane-parallel. NO __syncthreads in the 256-step loop.
//   - R25 fabric (fast path): flags via L2 — plain store (write-through) +
//     poll loop of {l1_inv; plain load} — the SAME mechanism the A-data
//     exchange uses (proven 256x176 times/launch). Agent-scope MIRROR word
//     (separate line) published too; consumer accepts it after 4 failed
//     primary spins => broken-primary degrades to ~baseline, not a hang.
//     Poll-loop inv subsumes the per-step A-freshness inv (every exit path
//     invs after the prior step's A-reads and before this step's A-reads).
//   - 176 blocks; swizzle g=bx&7, s=bx>>3; HW_REG_XCC_ID check selects fast
//     (same-XCD group) or slow (release/acquire agent) per group.
//   - d_ws: [8] grid barrier, [16..191] xcc, [256..2303] flags: per group g
//     256 ints at 256+g*256: [0..87] plain flags, [128..215] agent mirrors.
//
// Evidence ledger:
//   - R12: VALU heaters on 80 idle CUs = exact null -> DVFS theory dead.
//   - R13: fast=TRUE; dependent-FMA chain added FULL cost -> full clock.
//     Symmetric insertion adds fully regardless of slack => poll wait was
//     never measured; period = S(serial) + h(publish->detect hop).
//   - R15: agent atomics bypass L1 AND L2 (coherence point = L3/MALL) =>
//     current flag store ~700cyc + poll RT ~900cyc of L3 on every step.
//   - R17: sc0-only flags never observed (sc0 loads hit stale L1). Working
//     observation paths: agent atomics (L3) or l1_inv+plain (L2 — the
//     A-data path). R8's old falsification was a mixed-scope artifact;
//     R9's old inv+plain-flag falsification predates this structure =>
//     retest with insurance (this round).
//   - R18 probe: RT_agent ~570-900 cyc.
//   - R19: nt emb loads regressed (22x L2 reuse). Default alloc: VGPR 68,
//     prefetch structures never materialize.
//   - R20/R21: >256-VGPR hoists spill to scratch (arch ceiling).
//   - R22: + amdgpu_waves_per_eu(1,1): VGPR 68->132, ring-8 real,
//     2080->1940us (-7%).
//   - R23: l1_inv position off detect->A edge: NULL (1930us).
//   - R24: z-gate B-hoist: conflicts -27% (exact share) but dur +35us =>
//     LDS issue/conflicts NOT binding (2nd confirmation). REVERTED.
//   - R25 decode: primary works => hop 1.6K->~0.5K cyc, dur ~1750-1850.
//     primary broken => every step pays 4 spins + mirror RT: dur
//     ~2050-2150 (clear signal, no hang) -> revert fabric next round.
// ---------------------------------------------------------------------------

typedef unsigned short ushort_t;
typedef __bf16 bf16x8 __attribute__((ext_vector_type(8)));
typedef unsigned short ushort8 __attribute__((ext_vector_type(8)));
typedef float floatx4 __attribute__((ext_vector_type(4)));

#define NGRP   8
#define NSLC   22
#define NBLK   176
#define SB     840   // LDS row stride (bf16): 832 + 8 pad
#define HP     704
#define AH_ROW 1408  // hi[704] | lo[704]
#define PHASE  (256 * AH_ROW)
#define FLAGW(gg, ss, ww) (256 + (gg) * 256 + (ss) * 4 + (ww))
#define MIRROFF 128   // agent-scope mirror offset within a group's region

__device__ __forceinline__ float bf2f(ushort_t u) {
    unsigned v = ((unsigned)u) << 16; float f; __builtin_memcpy(&f, &v, 4); return f;
}
__device__ __forceinline__ ushort_t f2bf(float f) {
    unsigned u; __builtin_memcpy(&u, &f, 4);
    unsigned r = u + 0x7fff + ((u >> 16) & 1);
    return (ushort_t)(r >> 16);
}
__device__ __forceinline__ bf16x8 ld8(const ushort_t* p) {
    return __builtin_bit_cast(bf16x8, *(const ushort8*)p);
}
__device__ __forceinline__ bf16x8 cvt8(floatx4 a, floatx4 b) {
    ushort8 r = {f2bf(a.x), f2bf(a.y), f2bf(a.z), f2bf(a.w),
                 f2bf(b.x), f2bf(b.y), f2bf(b.z), f2bf(b.w)};
    return __builtin_bit_cast(bf16x8, r);
}
__device__ __forceinline__ void l1_inv() {
    asm volatile("buffer_inv sc0" ::: "memory");
}
__device__ __forceinline__ void wave_drain() {   // wave-local store drain
    asm volatile("s_waitcnt vmcnt(0)" ::: "memory");
}
__device__ __forceinline__ float fast_rcp(float x) {
    float r; asm("v_rcp_f32 %0, %1" : "=v"(r) : "v"(x)); return r;
}
__device__ __forceinline__ float fast_exp(float x) {
    float r; asm("v_exp_f32 %0, %1" : "=v"(r) : "v"(x * 1.44269504f)); return r;
}

__global__ void init_cnt(int* cnt) {
    for (int i = threadIdx.x; i < 2304; i += 1024) cnt[i] = 0;
}

__global__ __attribute__((amdgpu_waves_per_eu(1, 1)))
__launch_bounds__(256) void gru_main(
    const int* __restrict__ enc, const float* __restrict__ emb,
    const float* __restrict__ Wx, float* whf,
    const float* __restrict__ lab, const float* __restrict__ W1,
    const float* __restrict__ b1, const float* __restrict__ bias,
    float* __restrict__ out, int* cnt) {

    extern __shared__ ushort_t Bs[];   // [96][SB] bf16
    const int bx = blockIdx.x;
    const int g = bx & 7, s = bx >> 3;
    const int tid = threadIdx.x;
    const int wave = tid >> 6, lane = tid & 63;
    const int rt = wave >> 1, ct = wave & 1;
    const int q = lane >> 4, m = lane & 15;

    // ---- one-time staging: Bs[p][k] = bf16(W[k][col(p)]), p = gate*32+c ----
    for (int idx = tid; idx < 96 * 832; idx += 256) {
        int p = idx % 96, k = idx / 96;
        int c = s * 32 + (p & 31);
        ushort_t v = 0;
        if (c < 700) {
            int col = (p >> 5) * 700 + c;
            if (k < 100) v = f2bf(Wx[k * 2100 + col]);
            else if (k >= 128 && k < 828) v = f2bf(whf[(k - 128) * 2100 + col]);
        }
        Bs[p * SB + k] = v;
    }
    __syncthreads();   // all Wh reads of this block retired

    // ---- publish xcc id, then grid barrier (agent scope, one-time) ---------
    if (tid == 0) {
        int xcc;
        asm("s_getreg_b32 %0, hwreg(HW_REG_XCC_ID)" : "=s"(xcc));
        __hip_atomic_store(cnt + 16 + bx, xcc, __ATOMIC_RELAXED, __HIP_MEMORY_SCOPE_AGENT);
        __hip_atomic_fetch_add(cnt + 8, 1, __ATOMIC_ACQ_REL, __HIP_MEMORY_SCOPE_AGENT);
        while (__hip_atomic_load(cnt + 8, __ATOMIC_ACQUIRE, __HIP_MEMORY_SCOPE_AGENT) < NBLK)
            __builtin_amdgcn_s_sleep(1);
    }
    __syncthreads();

    // ---- fast iff all 22 peers share an XCD --------------------------------
    bool fast = true;
    {
        int myx = __hip_atomic_load(cnt + 16 + bx, __ATOMIC_RELAXED, __HIP_MEMORY_SCOPE_AGENT);
        for (int s2 = 0; s2 < NSLC; ++s2) {
            int px = __hip_atomic_load(cnt + 16 + g + 8 * s2, __ATOMIC_RELAXED, __HIP_MEMORY_SCOPE_AGENT);
            fast = fast && (px == myx);
        }
    }

    const int j = s * 32 + ct * 16 + m;
    float bzc = 0.f, brc = 0.f, b0h = 0.f, b1h = 0.f;
    if (j < 700) {
        bzc = bias[j] + bias[2100 + j];
        brc = bias[700 + j] + bias[2800 + j];
        b0h = bias[1400 + j];
        b1h = bias[3500 + j];
    }
    const int rowa = g * 32 + rt * 16 + m;

    ushort_t* Ah = (ushort_t*)whf;
    int* myflag = cnt + FLAGW(g, s, wave);
    int* mymirr = myflag + MIRROFF;
    // consumer wave rt needs flags (s2, rt*2+ct') for s2=0..21, ct'=0..1
    int* pollp = (lane < 44)
               ? (cnt + FLAGW(g, lane >> 1, rt * 2 + (lane & 1)))
               : (int*)nullptr;
    int* pollm = pollp ? pollp + MIRROFF : (int*)nullptr;

    // ---- h0; publish hi/lo to phase 0 (per-wave) ---------------------------
    float hown[4];
#pragma unroll
    for (int i = 0; i < 4; i++) {
        int rowc = g * 32 + rt * 16 + q * 4 + i;
        float v = 0.f;
        if (j < 200) v = lab[rowc] * W1[j] + b1[j];
        hown[i] = v;
        ushort_t hi = f2bf(v);
        Ah[rowc * AH_ROW + j] = hi;
        Ah[rowc * AH_ROW + HP + j] = f2bf(v - bf2f(hi));
    }
    if (fast) {
        wave_drain();
        if (lane == 0) {
            *(volatile int*)myflag = 1;   // plain store -> L2 (write-through)
            __hip_atomic_store(mymirr, 1, __ATOMIC_RELAXED, __HIP_MEMORY_SCOPE_AGENT);
        }
    } else {
        if (lane == 0)
            __hip_atomic_store(myflag, 1, __ATOMIC_RELEASE, __HIP_MEMORY_SCOPE_AGENT);
        else
            __threadfence();
    }

    const ushort_t* bsz = Bs + (ct * 16 + m) * SB;
    const ushort_t* bsr = Bs + (32 + ct * 16 + m) * SB;
    const ushort_t* bsh = Bs + (64 + ct * 16 + m) * SB;

    // ---- initial x prefetch for t=0 ----------------------------------------
    floatx4 pf[6]; floatx4 pft;
    {
        int tok = enc[rowa * 256 + 0];
        const float* ep = emb + tok * 100;
#pragma unroll
        for (int kt = 0; kt < 3; ++kt) {
            pf[kt * 2]     = *(const floatx4*)(ep + kt * 32 + q * 8);
            pf[kt * 2 + 1] = *(const floatx4*)(ep + kt * 32 + q * 8 + 4);
        }
        pft = *(const floatx4*)(ep + 96);
    }

    for (int t = 0; t < 256; ++t) {
        const ushort_t* Asrc = Ah + (t & 1) * PHASE;
        ushort_t* Adst = Ah + ((t + 1) & 1) * PHASE;
        floatx4 accz = {0,0,0,0}, accr = {0,0,0,0}, accrh = {0,0,0,0}, accxh = {0,0,0,0};

        // x-part from prefetched registers (off the critical chain)
#pragma unroll
        for (int kt = 0; kt < 3; ++kt) {
            bf16x8 a = cvt8(pf[kt * 2], pf[kt * 2 + 1]);
            int kb = kt * 32 + q * 8;
            accz  = __builtin_amdgcn_mfma_f32_16x16x32_bf16(a, ld8(bsz + kb), accz, 0, 0, 0);
            accr  = __builtin_amdgcn_mfma_f32_16x16x32_bf16(a, ld8(bsr + kb), accr, 0, 0, 0);
            accxh = __builtin_amdgcn_mfma_f32_16x16x32_bf16(a, ld8(bsh + kb), accxh, 0, 0, 0);
        }
        {
            ushort8 t8 = {0, 0, 0, 0, 0, 0, 0, 0};
            if (q == 0) {
                t8[0] = f2bf(pft.x); t8[1] = f2bf(pft.y);
                t8[2] = f2bf(pft.z); t8[3] = f2bf(pft.w);
            }
            bf16x8 a = __builtin_bit_cast(bf16x8, t8);
            int kb = 96 + q * 8;
            accz  = __builtin_amdgcn_mfma_f32_16x16x32_bf16(a, ld8(bsz + kb), accz, 0, 0, 0);
            accr  = __builtin_amdgcn_mfma_f32_16x16x32_bf16(a, ld8(bsr + kb), accr, 0, 0, 0);
            accxh = __builtin_amdgcn_mfma_f32_16x16x32_bf16(a, ld8(bsh + kb), accxh, 0, 0, 0);
        }
        // prefetch x for t+1 (in flight during the wait)
        {
            int tn = (t < 255) ? t + 1 : 255;
            int tok = enc[rowa * 256 + tn];
            const float* ep = emb + tok * 100;
#pragma unroll
            for (int kt = 0; kt < 3; ++kt) {
                pf[kt * 2]     = *(const floatx4*)(ep + kt * 32 + q * 8);
                pf[kt * 2 + 1] = *(const floatx4*)(ep + kt * 32 + q * 8 + 4);
            }
            pft = *(const floatx4*)(ep + 96);
        }

        // wait (per-wave, lane-parallel over the 44 relevant producer waves).
        // R25 primary: {l1_inv; plain load} reads the flag from L2 (~300cyc
        // RT vs ~900 L3). After 4 failed spins also accept the agent mirror
        // (insurance). Every exit path has an inv between the previous
        // step's A-reads and this step's A-reads => A-freshness is covered
        // here (standalone per-step inv removed).
        if (lane < 44) {
            if (fast) {
                int spin = 0;
                while (true) {
                    l1_inv();
                    if (*(volatile const int*)pollp >= t + 1) break;
                    if (++spin > 4) {
                        if (__hip_atomic_load(pollm, __ATOMIC_RELAXED,
                                              __HIP_MEMORY_SCOPE_AGENT) >= t + 1)
                            break;
                        __builtin_amdgcn_s_sleep(1);
                    }
                }
            } else {
                while (__hip_atomic_load(pollp, __ATOMIC_ACQUIRE, __HIP_MEMORY_SCOPE_AGENT) < t + 1)
                    __builtin_amdgcn_s_sleep(1);
            }
        }

        // h-part: 22 K-tiles; ring-buffer prefetch depth 8 of hi/lo A-frags
        const ushort_t* arow = Asrc + rowa * AH_ROW + q * 8;
        bf16x8 ra[8], rb[8];
#pragma unroll
        for (int p = 0; p < 8; ++p) {
            ra[p] = ld8(arow + p * 32);
            rb[p] = ld8(arow + HP + p * 32);
        }
#pragma unroll
        for (int kt = 0; kt < 22; ++kt) {
            bf16x8 ahi = ra[kt & 7];
            bf16x8 alo = rb[kt & 7];
            if (kt + 8 < 22) {
                ra[kt & 7] = ld8(arow + (kt + 8) * 32);
                rb[kt & 7] = ld8(arow + HP + (kt + 8) * 32);
            }
            int kb = 128 + kt * 32 + q * 8;
            bf16x8 bz8 = ld8(bsz + kb), br8 = ld8(bsr + kb), bh8 = ld8(bsh + kb);
            accz  = __builtin_amdgcn_mfma_f32_16x16x32_bf16(ahi, bz8, accz, 0, 0, 0);
            accr  = __builtin_amdgcn_mfma_f32_16x16x32_bf16(ahi, br8, accr, 0, 0, 0);
            accrh = __builtin_amdgcn_mfma_f32_16x16x32_bf16(ahi, bh8, accrh, 0, 0, 0);
            accz  = __builtin_amdgcn_mfma_f32_16x16x32_bf16(alo, bz8, accz, 0, 0, 0);
            accr  = __builtin_amdgcn_mfma_f32_16x16x32_bf16(alo, br8, accr, 0, 0, 0);
            accrh = __builtin_amdgcn_mfma_f32_16x16x32_bf16(alo, bh8, accrh, 0, 0, 0);
        }

        // epilogue: fast gates, update h, publish hi/lo
#pragma unroll
        for (int i = 0; i < 4; i++) {
            int rowc = g * 32 + rt * 16 + q * 4 + i;
            float z = fast_rcp(1.f + fast_exp(-(accz[i] + bzc)));
            float r = fast_rcp(1.f + fast_exp(-(accr[i] + brc)));
            float e2 = fast_exp(2.f * (accxh[i] + b0h + r * (accrh[i] + b1h)));
            float hh = 1.f - 2.f * fast_rcp(e2 + 1.f);
            float h = z * hown[i] + (1.f - z) * hh;
            if (j >= 700) h = 0.f;
            hown[i] = h;
            ushort_t hi = f2bf(h);
            Adst[rowc * AH_ROW + j] = hi;
            Adst[rowc * AH_ROW + HP + j] = f2bf(h - bf2f(hi));
        }

        // per-wave publish: drain own stores, then flag (plain L2 + mirror)
        if (fast) {
            wave_drain();
            if (lane == 0) {
                *(volatile int*)myflag = t + 2;   // plain -> L2
                __hip_atomic_store(mymirr, t + 2, __ATOMIC_RELAXED, __HIP_MEMORY_SCOPE_AGENT);
            }
        } else {
            if (lane == 0)
                __hip_atomic_store(myflag, t + 2, __ATOMIC_RELEASE, __HIP_MEMORY_SCOPE_AGENT);
            else
                __threadfence();
        }
    }

    // ---- final output -------------------------------------------------------
#pragma unroll
    for (int i = 0; i < 4; i++) {
        int rowc = g * 32 + rt * 16 + q * 4 + i;
        if (j >= 200 && j < 700)
            out[rowc * 500 + (j - 200)] = hown[i];
    }
}

extern "C" void kernel_launch(void* const* d_in, const int* in_sizes, int n_in,
                              void* d_out, int out_size, void* d_ws, size_t ws_size,
                              hipStream_t stream) {
    (void)in_sizes; (void)n_in; (void)out_size; (void)ws_size;
    const int*   enc  = (const int*)d_in[0];
    const float* lab  = (const float*)d_in[1];
    const float* emb  = (const float*)d_in[2];
    const float* W1   = (const float*)d_in[3];
    const float* b1   = (const float*)d_in[4];
    const float* Wx   = (const float*)d_in[5];
    float*       Wh   = (float*)d_in[6];
    const float* bias = (const float*)d_in[7];

    int*   cnt = (int*)d_ws;               // 9.2 KB of scratch used
    float* out = (float*)d_out;

    init_cnt<<<1, 1024, 0, stream>>>(cnt);

    hipFuncSetAttribute((const void*)gru_main,
                        hipFuncAttributeMaxDynamicSharedMemorySize, 96 * SB * 2);
    gru_main<<<NBLK, 256, 96 * SB * 2, stream>>>(enc, emb, Wx, Wh, lab, W1, b1,
                                                 bias, out, cnt);
}

// Round 15
// 1884.620 us; speedup vs baseline: 1.0489x; 1.0489x over previous
//
#include <hip/hip_runtime.h>

// ---------------------------------------------------------------------------
// Encoder: x=emb[enc]; xp = x@Wx + b_in; reset-after GRU over T=256 steps;
// out = h_last[:, 200:700].  All float inputs fp32; output fp32.
//
// Persistent weight-stationary GRU, per-WAVE dataflow sync (R11 fabric):
//   - Consumer wave rt reads ONLY its own 16 rows, produced by same-rt waves
//     of the 22 producer blocks. Producer drains own stores (vmcnt(0) is
//     wave-local) then publishes flag[g][slice][wave] (relaxed agent store);
//     consumer polls its 44 flags lane-parallel (relaxed agent loads), then
//     plain b128 A-ring (L1 freshness via end-of-step l1_inv, R23).
//   - 176 blocks; swizzle g=bx&7, s=bx>>3; HW_REG_XCC_ID check selects fast
//     (same-XCD group) or slow (release/acquire agent) per group.
//   - d_ws: [8] grid barrier, [16..191] xcc, [256..11519] wave flags —
//     R26: ONE 64B CACHE LINE PER FLAG (stride 16 ints). 46KB, zeroed by
//     init_cnt.
//
// Evidence ledger:
//   - R12: VALU heaters on 80 idle CUs = exact null -> DVFS theory dead.
//   - R13: fast=TRUE; dependent-FMA chain added FULL cost -> full clock.
//     Symmetric insertion adds fully => period = S(serial) + h(hop).
//   - R15: agent atomics bypass L1 AND L2 (coherence point = L3/MALL).
//   - R17+R25(+R8): L2-level flag observation falsified THREE ways (sc0
//     pair, inv+plain, mixed). Flags are locked to agent/L3; R25 also
//     showed volatile plain flag stores write through to HBM (+5.6MB
//     WRITE_SIZE) and cost ~+50us. Fabric reverted to R23 config.
//   - R18 probe: RT_agent ~570-900 cyc (measured UNDER poll contention).
//   - R19: nt emb loads regressed (22x L2 reuse). Default alloc: VGPR 68,
//     prefetch structures never materialize.
//   - R20/R21: >256-VGPR hoists spill to scratch (arch ceiling).
//   - R22: + amdgpu_waves_per_eu(1,1): VGPR 68->132, ring-8 real,
//     2080->1940us (-7%).
//   - R23: l1_inv position off detect->A edge: NULL; kept (1930us best).
//   - R24: z-gate B-hoist: conflicts -27% but no dur gain => LDS pressure
//     NOT binding (2nd confirmation). REVERTED.
//   - R26 (this round): L3 SAME-LINE CONTENTION theory. Flags are packed
//     16/line; per (g,rt) chain ~650 concurrent readers + 4 writers per
//     line every ~900cyc => L3 serializes same-line transactions, inflating
//     publish visibility AND poll RT (both on the hop h every step).
//     ONE-VARIABLE: pad each flag to its own 64B line (stride 16 ints):
//     readers/line 650->44, writers/line 4->1. Decode: dur ~1800-1880 =>
//     contention real (then try counter aggregation on top); dur ~1930 =>
//     contention falsified, hop is bare structural latency.
// ---------------------------------------------------------------------------

typedef unsigned short ushort_t;
typedef __bf16 bf16x8 __attribute__((ext_vector_type(8)));
typedef unsigned short ushort8 __attribute__((ext_vector_type(8)));
typedef float floatx4 __attribute__((ext_vector_type(4)));

#define NGRP   8
#define NSLC   22
#define NBLK   176
#define SB     840   // LDS row stride (bf16): 832 + 8 pad
#define HP     704
#define AH_ROW 1408  // hi[704] | lo[704]
#define PHASE  (256 * AH_ROW)
// R26: one 64B cache line per flag word: stride 16 ints.
#define FLAGW(gg, ss, ww) (256 + ((gg) * 88 + (ss) * 4 + (ww)) * 16)
#define CNT_N  (256 + NGRP * 88 * 16)   // 11520 ints = 46KB

__device__ __forceinline__ float bf2f(ushort_t u) {
    unsigned v = ((unsigned)u) << 16; float f; __builtin_memcpy(&f, &v, 4); return f;
}
__device__ __forceinline__ ushort_t f2bf(float f) {
    unsigned u; __builtin_memcpy(&u, &f, 4);
    unsigned r = u + 0x7fff + ((u >> 16) & 1);
    return (ushort_t)(r >> 16);
}
__device__ __forceinline__ bf16x8 ld8(const ushort_t* p) {
    return __builtin_bit_cast(bf16x8, *(const ushort8*)p);
}
__device__ __forceinline__ bf16x8 cvt8(floatx4 a, floatx4 b) {
    ushort8 r = {f2bf(a.x), f2bf(a.y), f2bf(a.z), f2bf(a.w),
                 f2bf(b.x), f2bf(b.y), f2bf(b.z), f2bf(b.w)};
    return __builtin_bit_cast(bf16x8, r);
}
__device__ __forceinline__ void l1_inv() {
    asm volatile("buffer_inv sc0" ::: "memory");
}
__device__ __forceinline__ void wave_drain() {   // wave-local store drain
    asm volatile("s_waitcnt vmcnt(0)" ::: "memory");
}
__device__ __forceinline__ float fast_rcp(float x) {
    float r; asm("v_rcp_f32 %0, %1" : "=v"(r) : "v"(x)); return r;
}
__device__ __forceinline__ float fast_exp(float x) {
    float r; asm("v_exp_f32 %0, %1" : "=v"(r) : "v"(x * 1.44269504f)); return r;
}

__global__ void init_cnt(int* cnt) {
    for (int i = threadIdx.x; i < CNT_N; i += 1024) cnt[i] = 0;
}

__global__ __attribute__((amdgpu_waves_per_eu(1, 1)))
__launch_bounds__(256) void gru_main(
    const int* __restrict__ enc, const float* __restrict__ emb,
    const float* __restrict__ Wx, float* whf,
    const float* __restrict__ lab, const float* __restrict__ W1,
    const float* __restrict__ b1, const float* __restrict__ bias,
    float* __restrict__ out, int* cnt) {

    extern __shared__ ushort_t Bs[];   // [96][SB] bf16
    const int bx = blockIdx.x;
    const int g = bx & 7, s = bx >> 3;
    const int tid = threadIdx.x;
    const int wave = tid >> 6, lane = tid & 63;
    const int rt = wave >> 1, ct = wave & 1;
    const int q = lane >> 4, m = lane & 15;

    // ---- one-time staging: Bs[p][k] = bf16(W[k][col(p)]), p = gate*32+c ----
    for (int idx = tid; idx < 96 * 832; idx += 256) {
        int p = idx % 96, k = idx / 96;
        int c = s * 32 + (p & 31);
        ushort_t v = 0;
        if (c < 700) {
            int col = (p >> 5) * 700 + c;
            if (k < 100) v = f2bf(Wx[k * 2100 + col]);
            else if (k >= 128 && k < 828) v = f2bf(whf[(k - 128) * 2100 + col]);
        }
        Bs[p * SB + k] = v;
    }
    __syncthreads();   // all Wh reads of this block retired

    // ---- publish xcc id, then grid barrier (agent scope, one-time) ---------
    if (tid == 0) {
        int xcc;
        asm("s_getreg_b32 %0, hwreg(HW_REG_XCC_ID)" : "=s"(xcc));
        __hip_atomic_store(cnt + 16 + bx, xcc, __ATOMIC_RELAXED, __HIP_MEMORY_SCOPE_AGENT);
        __hip_atomic_fetch_add(cnt + 8, 1, __ATOMIC_ACQ_REL, __HIP_MEMORY_SCOPE_AGENT);
        while (__hip_atomic_load(cnt + 8, __ATOMIC_ACQUIRE, __HIP_MEMORY_SCOPE_AGENT) < NBLK)
            __builtin_amdgcn_s_sleep(1);
    }
    __syncthreads();

    // ---- fast iff all 22 peers share an XCD --------------------------------
    bool fast = true;
    {
        int myx = __hip_atomic_load(cnt + 16 + bx, __ATOMIC_RELAXED, __HIP_MEMORY_SCOPE_AGENT);
        for (int s2 = 0; s2 < NSLC; ++s2) {
            int px = __hip_atomic_load(cnt + 16 + g + 8 * s2, __ATOMIC_RELAXED, __HIP_MEMORY_SCOPE_AGENT);
            fast = fast && (px == myx);
        }
    }

    const int j = s * 32 + ct * 16 + m;
    float bzc = 0.f, brc = 0.f, b0h = 0.f, b1h = 0.f;
    if (j < 700) {
        bzc = bias[j] + bias[2100 + j];
        brc = bias[700 + j] + bias[2800 + j];
        b0h = bias[1400 + j];
        b1h = bias[3500 + j];
    }
    const int rowa = g * 32 + rt * 16 + m;

    ushort_t* Ah = (ushort_t*)whf;
    int* myflag = cnt + FLAGW(g, s, wave);
    // consumer wave rt needs flags (s2, rt*2+ct') for s2=0..21, ct'=0..1
    int* pollp = (lane < 44)
               ? (cnt + FLAGW(g, lane >> 1, rt * 2 + (lane & 1)))
               : (int*)nullptr;

    // ---- h0; publish hi/lo to phase 0 (per-wave) ---------------------------
    float hown[4];
#pragma unroll
    for (int i = 0; i < 4; i++) {
        int rowc = g * 32 + rt * 16 + q * 4 + i;
        float v = 0.f;
        if (j < 200) v = lab[rowc] * W1[j] + b1[j];
        hown[i] = v;
        ushort_t hi = f2bf(v);
        Ah[rowc * AH_ROW + j] = hi;
        Ah[rowc * AH_ROW + HP + j] = f2bf(v - bf2f(hi));
    }
    if (fast) {
        wave_drain();
        if (lane == 0)
            __hip_atomic_store(myflag, 1, __ATOMIC_RELAXED, __HIP_MEMORY_SCOPE_AGENT);
    } else {
        if (lane == 0)
            __hip_atomic_store(myflag, 1, __ATOMIC_RELEASE, __HIP_MEMORY_SCOPE_AGENT);
        else
            __threadfence();
    }

    const ushort_t* bsz = Bs + (ct * 16 + m) * SB;
    const ushort_t* bsr = Bs + (32 + ct * 16 + m) * SB;
    const ushort_t* bsh = Bs + (64 + ct * 16 + m) * SB;

    // ---- initial x prefetch for t=0 ----------------------------------------
    floatx4 pf[6]; floatx4 pft;
    {
        int tok = enc[rowa * 256 + 0];
        const float* ep = emb + tok * 100;
#pragma unroll
        for (int kt = 0; kt < 3; ++kt) {
            pf[kt * 2]     = *(const floatx4*)(ep + kt * 32 + q * 8);
            pf[kt * 2 + 1] = *(const floatx4*)(ep + kt * 32 + q * 8 + 4);
        }
        pft = *(const floatx4*)(ep + 96);
    }

    // ---- R23: one-time inv before the loop — step 0's A-reads must not hit
    // stale staging-era whf lines in L1 (per-step inv at end of iter).
    if (fast) l1_inv();

    for (int t = 0; t < 256; ++t) {
        const ushort_t* Asrc = Ah + (t & 1) * PHASE;
        ushort_t* Adst = Ah + ((t + 1) & 1) * PHASE;
        floatx4 accz = {0,0,0,0}, accr = {0,0,0,0}, accrh = {0,0,0,0}, accxh = {0,0,0,0};

        // x-part from prefetched registers (off the critical chain)
#pragma unroll
        for (int kt = 0; kt < 3; ++kt) {
            bf16x8 a = cvt8(pf[kt * 2], pf[kt * 2 + 1]);
            int kb = kt * 32 + q * 8;
            accz  = __builtin_amdgcn_mfma_f32_16x16x32_bf16(a, ld8(bsz + kb), accz, 0, 0, 0);
            accr  = __builtin_amdgcn_mfma_f32_16x16x32_bf16(a, ld8(bsr + kb), accr, 0, 0, 0);
            accxh = __builtin_amdgcn_mfma_f32_16x16x32_bf16(a, ld8(bsh + kb), accxh, 0, 0, 0);
        }
        {
            ushort8 t8 = {0, 0, 0, 0, 0, 0, 0, 0};
            if (q == 0) {
                t8[0] = f2bf(pft.x); t8[1] = f2bf(pft.y);
                t8[2] = f2bf(pft.z); t8[3] = f2bf(pft.w);
            }
            bf16x8 a = __builtin_bit_cast(bf16x8, t8);
            int kb = 96 + q * 8;
            accz  = __builtin_amdgcn_mfma_f32_16x16x32_bf16(a, ld8(bsz + kb), accz, 0, 0, 0);
            accr  = __builtin_amdgcn_mfma_f32_16x16x32_bf16(a, ld8(bsr + kb), accr, 0, 0, 0);
            accxh = __builtin_amdgcn_mfma_f32_16x16x32_bf16(a, ld8(bsh + kb), accxh, 0, 0, 0);
        }
        // prefetch x for t+1 (in flight during the wait)
        {
            int tn = (t < 255) ? t + 1 : 255;
            int tok = enc[rowa * 256 + tn];
            const float* ep = emb + tok * 100;
#pragma unroll
            for (int kt = 0; kt < 3; ++kt) {
                pf[kt * 2]     = *(const floatx4*)(ep + kt * 32 + q * 8);
                pf[kt * 2 + 1] = *(const floatx4*)(ep + kt * 32 + q * 8 + 4);
            }
            pft = *(const floatx4*)(ep + 96);
        }

        // wait (per-wave, lane-parallel over the 44 relevant producer waves)
        if (lane < 44) {
            if (fast) {
                int spin = 0;
                while (__hip_atomic_load(pollp, __ATOMIC_RELAXED, __HIP_MEMORY_SCOPE_AGENT) < t + 1) {
                    if (++spin > 64) __builtin_amdgcn_s_sleep(1);
                }
            } else {
                while (__hip_atomic_load(pollp, __ATOMIC_ACQUIRE, __HIP_MEMORY_SCOPE_AGENT) < t + 1)
                    __builtin_amdgcn_s_sleep(1);
            }
        }
        // (inv for this step's A-reads happened at the end of the previous
        // iteration — nothing has touched A-addresses since.)

        // h-part: 22 K-tiles; ring-buffer prefetch depth 8 of hi/lo A-frags
        const ushort_t* arow = Asrc + rowa * AH_ROW + q * 8;
        bf16x8 ra[8], rb[8];
#pragma unroll
        for (int p = 0; p < 8; ++p) {
            ra[p] = ld8(arow + p * 32);
            rb[p] = ld8(arow + HP + p * 32);
        }
#pragma unroll
        for (int kt = 0; kt < 22; ++kt) {
            bf16x8 ahi = ra[kt & 7];
            bf16x8 alo = rb[kt & 7];
            if (kt + 8 < 22) {
                ra[kt & 7] = ld8(arow + (kt + 8) * 32);
                rb[kt & 7] = ld8(arow + HP + (kt + 8) * 32);
            }
            int kb = 128 + kt * 32 + q * 8;
            bf16x8 bz8 = ld8(bsz + kb), br8 = ld8(bsr + kb), bh8 = ld8(bsh + kb);
            accz  = __builtin_amdgcn_mfma_f32_16x16x32_bf16(ahi, bz8, accz, 0, 0, 0);
            accr  = __builtin_amdgcn_mfma_f32_16x16x32_bf16(ahi, br8, accr, 0, 0, 0);
            accrh = __builtin_amdgcn_mfma_f32_16x16x32_bf16(ahi, bh8, accrh, 0, 0, 0);
            accz  = __builtin_amdgcn_mfma_f32_16x16x32_bf16(alo, bz8, accz, 0, 0, 0);
            accr  = __builtin_amdgcn_mfma_f32_16x16x32_bf16(alo, br8, accr, 0, 0, 0);
            accrh = __builtin_amdgcn_mfma_f32_16x16x32_bf16(alo, bh8, accrh, 0, 0, 0);
        }

        // epilogue: fast gates, update h, publish hi/lo
#pragma unroll
        for (int i = 0; i < 4; i++) {
            int rowc = g * 32 + rt * 16 + q * 4 + i;
            float z = fast_rcp(1.f + fast_exp(-(accz[i] + bzc)));
            float r = fast_rcp(1.f + fast_exp(-(accr[i] + brc)));
            float e2 = fast_exp(2.f * (accxh[i] + b0h + r * (accrh[i] + b1h)));
            float hh = 1.f - 2.f * fast_rcp(e2 + 1.f);
            float h = z * hown[i] + (1.f - z) * hh;
            if (j >= 700) h = 0.f;
            hown[i] = h;
            ushort_t hi = f2bf(h);
            Adst[rowc * AH_ROW + j] = hi;
            Adst[rowc * AH_ROW + HP + j] = f2bf(h - bf2f(hi));
        }

        // per-wave publish: drain own stores, then flag
        if (fast) {
            wave_drain();
            if (lane == 0)
                __hip_atomic_store(myflag, t + 2, __ATOMIC_RELAXED, __HIP_MEMORY_SCOPE_AGENT);
        } else {
            if (lane == 0)
                __hip_atomic_store(myflag, t + 2, __ATOMIC_RELEASE, __HIP_MEMORY_SCOPE_AGENT);
            else
                __threadfence();
        }

        // ---- R23: end-of-step inv — L1 freshness for NEXT step's A-reads.
        if (fast) l1_inv();
    }

    // ---- final output -------------------------------------------------------
#pragma unroll
    for (int i = 0; i < 4; i++) {
        int rowc = g * 32 + rt * 16 + q * 4 + i;
        if (j >= 200 && j < 700)
            out[rowc * 500 + (j - 200)] = hown[i];
    }
}

extern "C" void kernel_launch(void* const* d_in, const int* in_sizes, int n_in,
                              void* d_out, int out_size, void* d_ws, size_t ws_size,
                              hipStream_t stream) {
    (void)in_sizes; (void)n_in; (void)out_size; (void)ws_size;
    const int*   enc  = (const int*)d_in[0];
    const float* lab  = (const float*)d_in[1];
    const float* emb  = (const float*)d_in[2];
    const float* W1   = (const float*)d_in[3];
    const float* b1   = (const float*)d_in[4];
    const float* Wx   = (const float*)d_in[5];
    float*       Wh   = (float*)d_in[6];
    const float* bias = (const float*)d_in[7];

    int*   cnt = (int*)d_ws;               // 46 KB of scratch used
    float* out = (float*)d_out;

    init_cnt<<<1, 1024, 0, stream>>>(cnt);

    hipFuncSetAttribute((const void*)gru_main,
                        hipFuncAttributeMaxDynamicSharedMemorySize, 96 * SB * 2);
    gru_main<<<NBLK, 256, 96 * SB * 2, stream>>>(enc, emb, Wx, Wh, lab, W1, b1,
                                                 bias, out, cnt);
}

// Round 16
// 1883.822 us; speedup vs baseline: 1.0494x; 1.0004x over previous
//
#include <hip/hip_runtime.h>

// ---------------------------------------------------------------------------
// Encoder: x=emb[enc]; xp = x@Wx + b_in; reset-after GRU over T=256 steps;
// out = h_last[:, 200:700].  All float inputs fp32; output fp32.
//
// Persistent weight-stationary GRU, per-WAVE dataflow sync (R11 fabric):
//   - Consumer wave rt reads ONLY its own 16 rows, produced by same-rt waves
//     of the 22 producer blocks. Producer drains own stores (vmcnt(0) is
//     wave-local) then publishes flag[g][slice][wave] (relaxed agent store);
//     consumer polls its 44 flags lane-parallel (relaxed agent loads), then
//     plain b128 A-ring (L1 freshness via end-of-step l1_inv, R23).
//   - 176 blocks; swizzle g=bx&7, s=bx>>3; HW_REG_XCC_ID check selects fast
//     (same-XCD group) or slow (release/acquire agent) per group.
//   - d_ws: [8] grid barrier, [16..191] xcc, flags at one 64B line per flag
//     (R26; 46KB, zeroed by init_cnt).
//
// Evidence ledger:
//   - R12: VALU heaters on 80 idle CUs = exact null -> DVFS theory dead.
//   - R13: fast=TRUE; dependent-FMA chain added FULL cost -> full clock.
//     Symmetric insertion adds fully => NO slack at the poll; every
//     pre-poll serial op is on the period. period = S(serial) + h(hop).
//   - R15: agent atomics bypass L1 AND L2 (coherence point = L3/MALL).
//   - R17+R25(+R8): L2-level flag observation falsified THREE ways. Flags
//     locked to agent/L3; R25: volatile plain flag stores write through to
//     HBM (+5.6MB WRITE) and cost +50us.
//   - R18 probe: RT_agent ~570-900 cyc.
//   - R19: nt emb loads regressed (22x L2 reuse). Default alloc: VGPR 68,
//     declared prefetch structures never materialize.
//   - R20/R21: oversized hoists spill to scratch; allocator acceptance with
//     waves_per_eu(1,1) observed up to ~180 VGPR.
//   - R22: + amdgpu_waves_per_eu(1,1): VGPR 68->132, ring-8 materialized,
//     2080->1940us (-7%).
//   - R23: l1_inv off the detect->A edge: NULL; kept at end-of-step (1930).
//   - R24: z-gate B-hoist: conflicts -27% but no gain => LDS pressure NOT
//     binding (2nd confirmation). REVERTED.
//   - R26: one 64B line per flag: 1930->1885us. L3 same-line contention on
//     the hop CONFIRMED (~175cyc/step). Hop now near bare structural cost.
//   - R27 (this round): S-side VALU cut + deeper ring.
//     (a) x-part cvt8 did ~250 software-f2bf VALU ops/step (~500+ cyc ON
//         the period per R13). Replace with v_cvt_pk_bf16_f32 (HW packed
//         RNE bf16 conversion, gfx950 asm-only): ~30 ops. Also epilogue hi
//         conversions.
//     (b) A-ring 8->12 (+32 VGPR -> ~164, inside the 180 acceptance):
//         refill distance 300->450cyc, fully covering post-inv L2 latency.
//     Decode: VGPR ~164 = ring real; VALUBusy -1pt = cvt real; dur
//     1790-1850 expected; null with both signatures => S not VALU/A-bound,
//     revisit poll structure (per-consumer flag replication) next.
// ---------------------------------------------------------------------------

typedef unsigned short ushort_t;
typedef __bf16 bf16x8 __attribute__((ext_vector_type(8)));
typedef unsigned short ushort8 __attribute__((ext_vector_type(8)));
typedef float floatx4 __attribute__((ext_vector_type(4)));

#define NGRP   8
#define NSLC   22
#define NBLK   176
#define SB     840   // LDS row stride (bf16): 832 + 8 pad
#define HP     704
#define AH_ROW 1408  // hi[704] | lo[704]
#define PHASE  (256 * AH_ROW)
// R26: one 64B cache line per flag word: stride 16 ints.
#define FLAGW(gg, ss, ww) (256 + ((gg) * 88 + (ss) * 4 + (ww)) * 16)
#define CNT_N  (256 + NGRP * 88 * 16)   // 11520 ints = 46KB

__device__ __forceinline__ float bf2f(ushort_t u) {
    unsigned v = ((unsigned)u) << 16; float f; __builtin_memcpy(&f, &v, 4); return f;
}
__device__ __forceinline__ ushort_t f2bf(float f) {
    unsigned u; __builtin_memcpy(&u, &f, 4);
    unsigned r = u + 0x7fff + ((u >> 16) & 1);
    return (ushort_t)(r >> 16);
}
// R27: HW packed f32->bf16 (RNE), 2 elems / instruction.
__device__ __forceinline__ unsigned cvtpk(float lo, float hi) {
    unsigned r;
    asm("v_cvt_pk_bf16_f32 %0, %1, %2" : "=v"(r) : "v"(lo), "v"(hi));
    return r;
}
__device__ __forceinline__ ushort_t f2bf_hw(float f) {
    return (ushort_t)cvtpk(f, f);
}
__device__ __forceinline__ bf16x8 ld8(const ushort_t* p) {
    return __builtin_bit_cast(bf16x8, *(const ushort8*)p);
}
__device__ __forceinline__ bf16x8 cvt8(floatx4 a, floatx4 b) {
    union { unsigned u[4]; ushort8 v; } r;
    r.u[0] = cvtpk(a.x, a.y);
    r.u[1] = cvtpk(a.z, a.w);
    r.u[2] = cvtpk(b.x, b.y);
    r.u[3] = cvtpk(b.z, b.w);
    return __builtin_bit_cast(bf16x8, r.v);
}
__device__ __forceinline__ void l1_inv() {
    asm volatile("buffer_inv sc0" ::: "memory");
}
__device__ __forceinline__ void wave_drain() {   // wave-local store drain
    asm volatile("s_waitcnt vmcnt(0)" ::: "memory");
}
__device__ __forceinline__ float fast_rcp(float x) {
    float r; asm("v_rcp_f32 %0, %1" : "=v"(r) : "v"(x)); return r;
}
__device__ __forceinline__ float fast_exp(float x) {
    float r; asm("v_exp_f32 %0, %1" : "=v"(r) : "v"(x * 1.44269504f)); return r;
}

__global__ void init_cnt(int* cnt) {
    for (int i = threadIdx.x; i < CNT_N; i += 1024) cnt[i] = 0;
}

__global__ __attribute__((amdgpu_waves_per_eu(1, 1)))
__launch_bounds__(256) void gru_main(
    const int* __restrict__ enc, const float* __restrict__ emb,
    const float* __restrict__ Wx, float* whf,
    const float* __restrict__ lab, const float* __restrict__ W1,
    const float* __restrict__ b1, const float* __restrict__ bias,
    float* __restrict__ out, int* cnt) {

    extern __shared__ ushort_t Bs[];   // [96][SB] bf16
    const int bx = blockIdx.x;
    const int g = bx & 7, s = bx >> 3;
    const int tid = threadIdx.x;
    const int wave = tid >> 6, lane = tid & 63;
    const int rt = wave >> 1, ct = wave & 1;
    const int q = lane >> 4, m = lane & 15;

    // ---- one-time staging: Bs[p][k] = bf16(W[k][col(p)]), p = gate*32+c ----
    for (int idx = tid; idx < 96 * 832; idx += 256) {
        int p = idx % 96, k = idx / 96;
        int c = s * 32 + (p & 31);
        ushort_t v = 0;
        if (c < 700) {
            int col = (p >> 5) * 700 + c;
            if (k < 100) v = f2bf(Wx[k * 2100 + col]);
            else if (k >= 128 && k < 828) v = f2bf(whf[(k - 128) * 2100 + col]);
        }
        Bs[p * SB + k] = v;
    }
    __syncthreads();   // all Wh reads of this block retired

    // ---- publish xcc id, then grid barrier (agent scope, one-time) ---------
    if (tid == 0) {
        int xcc;
        asm("s_getreg_b32 %0, hwreg(HW_REG_XCC_ID)" : "=s"(xcc));
        __hip_atomic_store(cnt + 16 + bx, xcc, __ATOMIC_RELAXED, __HIP_MEMORY_SCOPE_AGENT);
        __hip_atomic_fetch_add(cnt + 8, 1, __ATOMIC_ACQ_REL, __HIP_MEMORY_SCOPE_AGENT);
        while (__hip_atomic_load(cnt + 8, __ATOMIC_ACQUIRE, __HIP_MEMORY_SCOPE_AGENT) < NBLK)
            __builtin_amdgcn_s_sleep(1);
    }
    __syncthreads();

    // ---- fast iff all 22 peers share an XCD --------------------------------
    bool fast = true;
    {
        int myx = __hip_atomic_load(cnt + 16 + bx, __ATOMIC_RELAXED, __HIP_MEMORY_SCOPE_AGENT);
        for (int s2 = 0; s2 < NSLC; ++s2) {
            int px = __hip_atomic_load(cnt + 16 + g + 8 * s2, __ATOMIC_RELAXED, __HIP_MEMORY_SCOPE_AGENT);
            fast = fast && (px == myx);
        }
    }

    const int j = s * 32 + ct * 16 + m;
    float bzc = 0.f, brc = 0.f, b0h = 0.f, b1h = 0.f;
    if (j < 700) {
        bzc = bias[j] + bias[2100 + j];
        brc = bias[700 + j] + bias[2800 + j];
        b0h = bias[1400 + j];
        b1h = bias[3500 + j];
    }
    const int rowa = g * 32 + rt * 16 + m;

    ushort_t* Ah = (ushort_t*)whf;
    int* myflag = cnt + FLAGW(g, s, wave);
    // consumer wave rt needs flags (s2, rt*2+ct') for s2=0..21, ct'=0..1
    int* pollp = (lane < 44)
               ? (cnt + FLAGW(g, lane >> 1, rt * 2 + (lane & 1)))
               : (int*)nullptr;

    // ---- h0; publish hi/lo to phase 0 (per-wave) ---------------------------
    float hown[4];
#pragma unroll
    for (int i = 0; i < 4; i++) {
        int rowc = g * 32 + rt * 16 + q * 4 + i;
        float v = 0.f;
        if (j < 200) v = lab[rowc] * W1[j] + b1[j];
        hown[i] = v;
        ushort_t hi = f2bf(v);
        Ah[rowc * AH_ROW + j] = hi;
        Ah[rowc * AH_ROW + HP + j] = f2bf(v - bf2f(hi));
    }
    if (fast) {
        wave_drain();
        if (lane == 0)
            __hip_atomic_store(myflag, 1, __ATOMIC_RELAXED, __HIP_MEMORY_SCOPE_AGENT);
    } else {
        if (lane == 0)
            __hip_atomic_store(myflag, 1, __ATOMIC_RELEASE, __HIP_MEMORY_SCOPE_AGENT);
        else
            __threadfence();
    }

    const ushort_t* bsz = Bs + (ct * 16 + m) * SB;
    const ushort_t* bsr = Bs + (32 + ct * 16 + m) * SB;
    const ushort_t* bsh = Bs + (64 + ct * 16 + m) * SB;

    // ---- initial x prefetch for t=0 ----------------------------------------
    floatx4 pf[6]; floatx4 pft;
    {
        int tok = enc[rowa * 256 + 0];
        const float* ep = emb + tok * 100;
#pragma unroll
        for (int kt = 0; kt < 3; ++kt) {
            pf[kt * 2]     = *(const floatx4*)(ep + kt * 32 + q * 8);
            pf[kt * 2 + 1] = *(const floatx4*)(ep + kt * 32 + q * 8 + 4);
        }
        pft = *(const floatx4*)(ep + 96);
    }

    // ---- R23: one-time inv before the loop — step 0's A-reads must not hit
    // stale staging-era whf lines in L1 (per-step inv at end of iter).
    if (fast) l1_inv();

    for (int t = 0; t < 256; ++t) {
        const ushort_t* Asrc = Ah + (t & 1) * PHASE;
        ushort_t* Adst = Ah + ((t + 1) & 1) * PHASE;
        floatx4 accz = {0,0,0,0}, accr = {0,0,0,0}, accrh = {0,0,0,0}, accxh = {0,0,0,0};

        // x-part from prefetched registers (R27: HW cvt_pk bf16 packing)
#pragma unroll
        for (int kt = 0; kt < 3; ++kt) {
            bf16x8 a = cvt8(pf[kt * 2], pf[kt * 2 + 1]);
            int kb = kt * 32 + q * 8;
            accz  = __builtin_amdgcn_mfma_f32_16x16x32_bf16(a, ld8(bsz + kb), accz, 0, 0, 0);
            accr  = __builtin_amdgcn_mfma_f32_16x16x32_bf16(a, ld8(bsr + kb), accr, 0, 0, 0);
            accxh = __builtin_amdgcn_mfma_f32_16x16x32_bf16(a, ld8(bsh + kb), accxh, 0, 0, 0);
        }
        {
            union { unsigned u[4]; ushort8 v; } t8;
            t8.u[0] = 0; t8.u[1] = 0; t8.u[2] = 0; t8.u[3] = 0;
            if (q == 0) {
                t8.u[0] = cvtpk(pft.x, pft.y);
                t8.u[1] = cvtpk(pft.z, pft.w);
            }
            bf16x8 a = __builtin_bit_cast(bf16x8, t8.v);
            int kb = 96 + q * 8;
            accz  = __builtin_amdgcn_mfma_f32_16x16x32_bf16(a, ld8(bsz + kb), accz, 0, 0, 0);
            accr  = __builtin_amdgcn_mfma_f32_16x16x32_bf16(a, ld8(bsr + kb), accr, 0, 0, 0);
            accxh = __builtin_amdgcn_mfma_f32_16x16x32_bf16(a, ld8(bsh + kb), accxh, 0, 0, 0);
        }
        // prefetch x for t+1 (in flight during the wait)
        {
            int tn = (t < 255) ? t + 1 : 255;
            int tok = enc[rowa * 256 + tn];
            const float* ep = emb + tok * 100;
#pragma unroll
            for (int kt = 0; kt < 3; ++kt) {
                pf[kt * 2]     = *(const floatx4*)(ep + kt * 32 + q * 8);
                pf[kt * 2 + 1] = *(const floatx4*)(ep + kt * 32 + q * 8 + 4);
            }
            pft = *(const floatx4*)(ep + 96);
        }

        // wait (per-wave, lane-parallel over the 44 relevant producer waves)
        if (lane < 44) {
            if (fast) {
                int spin = 0;
                while (__hip_atomic_load(pollp, __ATOMIC_RELAXED, __HIP_MEMORY_SCOPE_AGENT) < t + 1) {
                    if (++spin > 64) __builtin_amdgcn_s_sleep(1);
                }
            } else {
                while (__hip_atomic_load(pollp, __ATOMIC_ACQUIRE, __HIP_MEMORY_SCOPE_AGENT) < t + 1)
                    __builtin_amdgcn_s_sleep(1);
            }
        }
        // (inv for this step's A-reads happened at the end of the previous
        // iteration — nothing has touched A-addresses since.)

        // h-part: 22 K-tiles; ring-buffer prefetch depth 12 (R27) of hi/lo
        // A-frags: refill distance ~450cyc covers post-inv L2 latency.
        const ushort_t* arow = Asrc + rowa * AH_ROW + q * 8;
        bf16x8 ra[12], rb[12];
#pragma unroll
        for (int p = 0; p < 12; ++p) {
            ra[p] = ld8(arow + p * 32);
            rb[p] = ld8(arow + HP + p * 32);
        }
#pragma unroll
        for (int kt = 0; kt < 22; ++kt) {
            bf16x8 ahi = ra[kt % 12];
            bf16x8 alo = rb[kt % 12];
            if (kt + 12 < 22) {
                ra[kt % 12] = ld8(arow + (kt + 12) * 32);
                rb[kt % 12] = ld8(arow + HP + (kt + 12) * 32);
            }
            int kb = 128 + kt * 32 + q * 8;
            bf16x8 bz8 = ld8(bsz + kb), br8 = ld8(bsr + kb), bh8 = ld8(bsh + kb);
            accz  = __builtin_amdgcn_mfma_f32_16x16x32_bf16(ahi, bz8, accz, 0, 0, 0);
            accr  = __builtin_amdgcn_mfma_f32_16x16x32_bf16(ahi, br8, accr, 0, 0, 0);
            accrh = __builtin_amdgcn_mfma_f32_16x16x32_bf16(ahi, bh8, accrh, 0, 0, 0);
            accz  = __builtin_amdgcn_mfma_f32_16x16x32_bf16(alo, bz8, accz, 0, 0, 0);
            accr  = __builtin_amdgcn_mfma_f32_16x16x32_bf16(alo, br8, accr, 0, 0, 0);
            accrh = __builtin_amdgcn_mfma_f32_16x16x32_bf16(alo, bh8, accrh, 0, 0, 0);
        }

        // epilogue: fast gates, update h, publish hi/lo (R27: HW f2bf)
#pragma unroll
        for (int i = 0; i < 4; i++) {
            int rowc = g * 32 + rt * 16 + q * 4 + i;
            float z = fast_rcp(1.f + fast_exp(-(accz[i] + bzc)));
            float r = fast_rcp(1.f + fast_exp(-(accr[i] + brc)));
            float e2 = fast_exp(2.f * (accxh[i] + b0h + r * (accrh[i] + b1h)));
            float hh = 1.f - 2.f * fast_rcp(e2 + 1.f);
            float h = z * hown[i] + (1.f - z) * hh;
            if (j >= 700) h = 0.f;
            hown[i] = h;
            ushort_t hi = f2bf_hw(h);
            Adst[rowc * AH_ROW + j] = hi;
            Adst[rowc * AH_ROW + HP + j] = f2bf_hw(h - bf2f(hi));
        }

        // per-wave publish: drain own stores, then flag
        if (fast) {
            wave_drain();
            if (lane == 0)
                __hip_atomic_store(myflag, t + 2, __ATOMIC_RELAXED, __HIP_MEMORY_SCOPE_AGENT);
        } else {
            if (lane == 0)
                __hip_atomic_store(myflag, t + 2, __ATOMIC_RELEASE, __HIP_MEMORY_SCOPE_AGENT);
            else
                __threadfence();
        }

        // ---- R23: end-of-step inv — L1 freshness for NEXT step's A-reads.
        if (fast) l1_inv();
    }

    // ---- final output -------------------------------------------------------
#pragma unroll
    for (int i = 0; i < 4; i++) {
        int rowc = g * 32 + rt * 16 + q * 4 + i;
        if (j >= 200 && j < 700)
            out[rowc * 500 + (j - 200)] = hown[i];
    }
}

extern "C" void kernel_launch(void* const* d_in, const int* in_sizes, int n_in,
                              void* d_out, int out_size, void* d_ws, size_t ws_size,
                              hipStream_t stream) {
    (void)in_sizes; (void)n_in; (void)out_size; (void)ws_size;
    const int*   enc  = (const int*)d_in[0];
    const float* lab  = (const float*)d_in[1];
    const float* emb  = (const float*)d_in[2];
    const float* W1   = (const float*)d_in[3];
    const float* b1   = (const float*)d_in[4];
    const float* Wx   = (const float*)d_in[5];
    float*       Wh   = (float*)d_in[6];
    const float* bias = (const float*)d_in[7];

    int*   cnt = (int*)d_ws;               // 46 KB of scratch used
    float* out = (float*)d_out;

    init_cnt<<<1, 1024, 0, stream>>>(cnt);

    hipFuncSetAttribute((const void*)gru_main,
                        hipFuncAttributeMaxDynamicSharedMemorySize, 96 * SB * 2);
    gru_main<<<NBLK, 256, 96 * SB * 2, stream>>>(enc, emb, Wx, Wh, lab, W1, b1,
                                                 bias, out, cnt);
}